// Round 4
// baseline (268.922 us; speedup 1.0000x reference)
//
#include <hip/hip_runtime.h>

#define BB 128
#define LL 256
#define DD 384
#define QB 64

typedef __attribute__((ext_vector_type(8))) short bf16x8;
typedef __attribute__((ext_vector_type(4))) short bf16x4;
typedef __attribute__((ext_vector_type(4))) float f32x4;
typedef __attribute__((ext_vector_type(4))) uint  u32x4;

union frag_u { u32x4 u; bf16x8 s; };

__device__ inline uint f2bf_rne(float x) {
  uint u = __float_as_uint(x);
  return (u + 0x7FFFu + ((u >> 16) & 1u)) >> 16;
}

// 8 fp32 -> bf16 hi (truncate) + bf16 lo (residual, truncate)
__device__ inline void split8(float4 v0, float4 v1, bf16x8& hi, bf16x8& lo) {
  float f[8] = {v0.x, v0.y, v0.z, v0.w, v1.x, v1.y, v1.z, v1.w};
  frag_u h, l;
  #pragma unroll
  for (int p = 0; p < 4; ++p) {
    uint ua = __float_as_uint(f[2 * p]), ub = __float_as_uint(f[2 * p + 1]);
    h.u[p] = __builtin_amdgcn_perm(ub, ua, 0x07060302);
    float la = f[2 * p]     - __uint_as_float(ua & 0xFFFF0000u);
    float lb = f[2 * p + 1] - __uint_as_float(ub & 0xFFFF0000u);
    l.u[p] = __builtin_amdgcn_perm(__float_as_uint(lb), __float_as_uint(la), 0x07060302);
  }
  hi = h.s; lo = l.s;
}

// 8-bf16 fragment from two ds_read_b64 (8B-aligned rows)
__device__ inline bf16x8 ld_frag8(const short* p) {
  bf16x4 lo = *(const bf16x4*)p;
  bf16x4 hi = *(const bf16x4*)(p + 4);
  bf16x8 r;
  r[0] = lo[0]; r[1] = lo[1]; r[2] = lo[2]; r[3] = lo[3];
  r[4] = hi[0]; r[5] = hi[1]; r[6] = hi[2]; r[7] = hi[3];
  return r;
}

#define MFMA __builtin_amdgcn_mfma_f32_16x16x32_bf16

// One block per (batch, side, 64-row tile). 512 threads = 8 waves, wave-grid 1x8.
__global__ __launch_bounds__(512, 4) void fused_kernel(
    const float* __restrict__ qf, const float* __restrict__ af,
    const int* __restrict__ qm, const int* __restrict__ am,
    float* __restrict__ accum)
{
  // XCD-affine decode: xcd = bid&7 = b&7 -> all 8 tiles of a batch on one XCD
  const int bid = blockIdx.x;
  const int blo = bid & 7, r1 = bid >> 3;
  const int tl = r1 & 7, bhi = r1 >> 3;
  const int b = bhi * 8 + blo;
  const int side = tl >> 2, r0 = (tl & 3) * QB;

  const float* self = side ? af : qf;   // rows we attend FROM
  const float* feat = side ? qf : af;   // rows we attend TO
  const int*   msk  = side ? am : qm;

  __shared__ __align__(16) short sAl[32 * QB * 8];  // 32KB: P in A-frag layout [c8][row][j]
  __shared__ __align__(16) short sVt[DD][36];       // 27.6KB: featT chunk [d][k], 32k + pad
  __shared__ float sRedM[8][QB];
  __shared__ float sRedS[8][QB];
  __shared__ float sInv[QB];
  __shared__ float sSsq[QB];
  __shared__ float sPool[DD];

  const int t = threadIdx.x;
  const int w = t >> 6, lane = t & 63;
  const int lam = lane & 15, g = lane >> 4;

  const float* selfb = self + ((size_t)b * LL + r0) * DD;
  const float* featb = feat + (size_t)b * LL * DD;

  // ---------------- Phase A: scores, barrier-free, frags direct from global ----------------
  // wave w: rows rt*16+lam (rt=0..3), cols w*32 + ct*16 + lam (ct=0..1)
  f32x4 accS[4][2] = {};
  for (int kc = 0; kc < 12; ++kc) {
    const int kb = kc * 32 + g * 8;
    bf16x8 bh[2], bl[2];
    #pragma unroll
    for (int ct = 0; ct < 2; ++ct) {
      const float* p = featb + (size_t)(w * 32 + ct * 16 + lam) * DD + kb;
      split8(*(const float4*)p, *(const float4*)(p + 4), bh[ct], bl[ct]);
    }
    #pragma unroll
    for (int rt = 0; rt < 4; ++rt) {
      const float* p = selfb + (size_t)(rt * 16 + lam) * DD + kb;
      bf16x8 ah, al;
      split8(*(const float4*)p, *(const float4*)(p + 4), ah, al);
      #pragma unroll
      for (int ct = 0; ct < 2; ++ct) {
        accS[rt][ct] = MFMA(ah, bh[ct], accS[rt][ct], 0, 0, 0);
        accS[rt][ct] = MFMA(ah, bl[ct], accS[rt][ct], 0, 0, 0);
        accS[rt][ct] = MFMA(al, bh[ct], accS[rt][ct], 0, 0, 0);
      }
    }
  }

  // ---------------- Softmax over cols (C layout: col=lane&15, row=g*4+rg) ----------------
  #pragma unroll
  for (int rt = 0; rt < 4; ++rt)
    #pragma unroll
    for (int rg = 0; rg < 4; ++rg) {
      float m = fmaxf(accS[rt][0][rg], accS[rt][1][rg]);
      #pragma unroll
      for (int off = 1; off < 16; off <<= 1) m = fmaxf(m, __shfl_xor(m, off));
      if (lam == 0) sRedM[w][rt * 16 + g * 4 + rg] = m;
    }
  __syncthreads();
  #pragma unroll
  for (int rt = 0; rt < 4; ++rt)
    #pragma unroll
    for (int rg = 0; rg < 4; ++rg) {
      int row = rt * 16 + g * 4 + rg;
      float m = sRedM[0][row];
      #pragma unroll
      for (int ww = 1; ww < 8; ++ww) m = fmaxf(m, sRedM[ww][row]);
      float s = 0.f;
      #pragma unroll
      for (int ct = 0; ct < 2; ++ct) {
        float p = __expf(accS[rt][ct][rg] - m);
        accS[rt][ct][rg] = p;
        s += p;
      }
      #pragma unroll
      for (int off = 1; off < 16; off <<= 1) s += __shfl_xor(s, off);
      if (lam == 0) sRedS[w][row] = s;
    }
  __syncthreads();
  #pragma unroll
  for (int rt = 0; rt < 4; ++rt)
    #pragma unroll
    for (int rg = 0; rg < 4; ++rg) {
      int row = rt * 16 + g * 4 + rg;
      float s = 0.f;
      #pragma unroll
      for (int ww = 0; ww < 8; ++ww) s += sRedS[ww][row];
      float inv = 1.f / s;
      #pragma unroll
      for (int ct = 0; ct < 2; ++ct) {
        int c = w * 32 + ct * 16 + lam;
        sAl[((c >> 3) * QB + row) * 8 + (c & 7)] = (short)f2bf_rne(accS[rt][ct][rg] * inv);
      }
    }
  __syncthreads();

  // ---------------- PV: O[64][384] = P @ feat, V via featT LDS transpose staging ----------------
  // wave w: d-cols w*48 + dt*16 + lam (dt=0..2)
  f32x4 accP[4][3] = {};
  for (int ac = 0; ac < 8; ++ac) {
    { // stage featT[d][k]: tokens ac*32..+32, packed token-pairs
      const int k0 = ac * 32;
      #pragma unroll
      for (int i = 0; i < 12; ++i) {
        int u = t + i * 512;
        int kp = u / 384, d = u - kp * 384;
        const float* fp = &featb[(size_t)(k0 + kp * 2) * DD + d];
        uint pk = f2bf_rne(fp[0]) | (f2bf_rne(fp[DD]) << 16);
        *(uint*)&sVt[d][kp * 2] = pk;
      }
    }
    __syncthreads();
    frag_u vf[3];
    #pragma unroll
    for (int dt = 0; dt < 3; ++dt)
      vf[dt].s = ld_frag8(&sVt[w * 48 + dt * 16 + lam][g * 8]);
    bf16x8 pf[4];
    #pragma unroll
    for (int rt = 0; rt < 4; ++rt)
      pf[rt] = *(const bf16x8*)&sAl[((ac * 4 + g) * QB + rt * 16 + lam) * 8];
    #pragma unroll
    for (int rt = 0; rt < 4; ++rt)
      #pragma unroll
      for (int dt = 0; dt < 3; ++dt)
        accP[rt][dt] = MFMA(pf[rt], vf[dt].s, accP[rt][dt], 0, 0, 0);
    __syncthreads();
  }

  // ---------------- Epilogue: row l2norm over [self|attended], masked pool ----------------
  #pragma unroll
  for (int rt = 0; rt < 4; ++rt)
    #pragma unroll
    for (int rg = 0; rg < 4; ++rg) {
      float s = 0.f;
      #pragma unroll
      for (int dt = 0; dt < 3; ++dt) s += accP[rt][dt][rg] * accP[rt][dt][rg];
      #pragma unroll
      for (int off = 1; off < 16; off <<= 1) s += __shfl_xor(s, off);
      if (lam == 0) sRedM[w][rt * 16 + g * 4 + rg] = s;
    }
  {
    int sr = t >> 3, sc = (t & 7) * 4;
    const float* sp = &selfb[(size_t)sr * DD];
    float ss = 0.f;
    #pragma unroll
    for (int j = 0; j < 12; ++j) {
      float4 v = *(const float4*)&sp[sc + j * 32];
      ss += v.x * v.x + v.y * v.y + v.z * v.z + v.w * v.w;
    }
    ss += __shfl_xor(ss, 1); ss += __shfl_xor(ss, 2); ss += __shfl_xor(ss, 4);
    if ((t & 7) == 0) sSsq[sr] = ss;
  }
  __syncthreads();
  if (t < QB) {
    float tot = sSsq[t];
    #pragma unroll
    for (int ww = 0; ww < 8; ++ww) tot += sRedM[ww][t];
    int mv = msk[(size_t)b * LL + r0 + t];
    sInv[t] = mv ? (1.f / fmaxf(sqrtf(tot), 1e-12f)) : 0.f;
  }
  __syncthreads();
  #pragma unroll
  for (int dt = 0; dt < 3; ++dt) {
    float pa = 0.f;
    #pragma unroll
    for (int rt = 0; rt < 4; ++rt)
      #pragma unroll
      for (int rg = 0; rg < 4; ++rg)
        pa += sInv[rt * 16 + g * 4 + rg] * accP[rt][dt][rg];
    pa += __shfl_xor(pa, 16);
    pa += __shfl_xor(pa, 32);
    if (g == 0) sPool[w * 48 + dt * 16 + lam] = pa;   // unique writer per d
  }
  __syncthreads();
  if (t < DD) {
    float* ac = accum + ((size_t)side * BB + b) * 2 * DD;
    float ps = 0.f;
    const float* sp = selfb + t;
    #pragma unroll 4
    for (int r = 0; r < QB; ++r) ps = fmaf(sInv[r], sp[(size_t)r * DD], ps);
    atomicAdd(&ac[t], ps);
    atomicAdd(&ac[DD + t], sPool[t]);
  }
}

// ---------------- Finalize: divide by mask count, final l2norm ----------------
__global__ __launch_bounds__(256) void finalize_kernel(
    const float* __restrict__ accum, const int* __restrict__ qm,
    const int* __restrict__ am, float* __restrict__ out)
{
  const int b    = blockIdx.x & (BB - 1);
  const int side = blockIdx.x >> 7;
  const int* msk = side ? am : qm;
  const int t = threadIdx.x;
  __shared__ float red[8];

  float c = (float)msk[(size_t)b * LL + t];
  #pragma unroll
  for (int off = 1; off < 64; off <<= 1) c += __shfl_xor(c, off);
  if ((t & 63) == 0) red[t >> 6] = c;
  __syncthreads();
  float cnt = fmaxf(red[0] + red[1] + red[2] + red[3], 1e-9f);

  const float* ac = accum + ((size_t)side * BB + b) * 2 * DD;
  float v[3];
  float ssq = 0.f;
  #pragma unroll
  for (int i = 0; i < 3; ++i) {
    v[i] = ac[t * 3 + i] / cnt;
    ssq += v[i] * v[i];
  }
  #pragma unroll
  for (int off = 1; off < 64; off <<= 1) ssq += __shfl_xor(ssq, off);
  __syncthreads();
  if ((t & 63) == 0) red[t >> 6] = ssq;
  __syncthreads();
  float n = sqrtf(red[0] + red[1] + red[2] + red[3]);
  float inv = 1.f / fmaxf(n, 1e-12f);
  float* ob = out + ((size_t)side * BB + b) * 2 * DD;
  #pragma unroll
  for (int i = 0; i < 3; ++i) ob[t * 3 + i] = v[i] * inv;
}

extern "C" void kernel_launch(void* const* d_in, const int* in_sizes, int n_in,
                              void* d_out, int out_size, void* d_ws, size_t ws_size,
                              hipStream_t stream) {
  const float* qf = (const float*)d_in[0];
  const float* af = (const float*)d_in[1];
  const int*   qm = (const int*)d_in[2];
  const int*   am = (const int*)d_in[3];
  float* out   = (float*)d_out;
  float* accum = (float*)d_ws;   // 2*128*768*4 = 786 KB

  hipMemsetAsync(accum, 0, sizeof(float) * 2 * BB * 2 * DD, stream);
  fused_kernel<<<dim3(1024), 512, 0, stream>>>(qf, af, qm, am, accum);
  finalize_kernel<<<256, 256, 0, stream>>>(accum, qm, am, out);
}

// Round 6
// 121.029 us; speedup vs baseline: 2.2220x; 2.2220x over previous
//
#include <hip/hip_runtime.h>

#define BB 128
#define LL 256
#define DD 384
#define QB 64

typedef __attribute__((ext_vector_type(8))) _Float16 half8;
typedef __attribute__((ext_vector_type(4))) float f32x4;
typedef __attribute__((ext_vector_type(4))) uint  u32x4;

union fragh { u32x4 u; half8 h; };

__device__ inline uint packrne(float a, float b) {
  _Float16 ha = (_Float16)a, hb = (_Float16)b;   // v_cvt_f16_f32 (RNE)
  return (uint)__builtin_bit_cast(unsigned short, ha) |
         ((uint)__builtin_bit_cast(unsigned short, hb) << 16);
}

__device__ inline uint packrtz(float a, float b) {
  auto h = __builtin_amdgcn_cvt_pkrtz(a, b);   // __fp16 ext_vector(2)
  return __builtin_bit_cast(uint, h);
}

// 8-half fragment from two 8B LDS reads (rows are 72B-strided, 8B-aligned)
__device__ inline half8 ld_frag8h(const short* p) {
  uint2 lo = *(const uint2*)p;
  uint2 hi = *(const uint2*)(p + 4);
  fragh f;
  f.u[0] = lo.x; f.u[1] = lo.y; f.u[2] = hi.x; f.u[3] = hi.y;
  return f.h;
}

#define MFMA16 __builtin_amdgcn_mfma_f32_16x16x32_f16

// One block per (batch, side, 64-row tile). 512 threads = 8 waves, wave-grid 1x8.
__global__ __launch_bounds__(512, 4) void fused_kernel(
    const float* __restrict__ qf, const float* __restrict__ af,
    const int* __restrict__ qm, const int* __restrict__ am,
    float* __restrict__ accum)
{
  // XCD-affine decode: xcd = bid&7 = b&7 -> all 8 tiles of a batch on one XCD
  const int bid = blockIdx.x;
  const int blo = bid & 7, r1 = bid >> 3;
  const int tl = r1 & 7, bhi = r1 >> 3;
  const int b = bhi * 8 + blo;
  const int side = tl >> 2, r0 = (tl & 3) * QB;

  const float* self = side ? af : qf;   // rows we attend FROM
  const float* feat = side ? qf : af;   // rows we attend TO
  const int*   msk  = side ? am : qm;

  // Staging region (27.6KB) unioned between Phase-A (sF/sS) and PV (sVt)
  __shared__ __align__(16) short sStage[DD][36];
  __shared__ __align__(16) short sAl[32 * QB * 8];  // 32KB: P fp16, A-frag layout [c8][row][8]
  __shared__ float sRedM[8][QB];
  __shared__ float sRedS[8][QB];
  __shared__ float sInv[QB];
  __shared__ float sSsq[QB];
  __shared__ float sPool[DD];

  short (*sF)[36] = sStage;          // feat fp16 [256][32+pad]
  short (*sS)[36] = &sStage[LL];     // self fp16 [64][32+pad]
  short (*sVt)[36] = sStage;         // PV: featT fp16 [384][32+pad]

  const int t = threadIdx.x;
  const int w = t >> 6, lane = t & 63;
  const int lam = lane & 15, g = lane >> 4;

  const float* selfb = self + ((size_t)b * LL + r0) * DD;
  const float* featb = feat + (size_t)b * LL * DD;

  // ---------------- Phase A: scores = self . feat^T, fp16 MFMA, LDS-staged ----------------
  const int tok8 = t >> 3;        // 0..63
  const int k4   = (t & 7) * 4;   // 0,4,..,28
  float4 fF[4], fS;

  #define LOADA(kc_) do {                                                         \
    const int k0_ = (kc_) * 32;                                                   \
    _Pragma("unroll")                                                             \
    for (int j = 0; j < 4; ++j)                                                   \
      fF[j] = *(const float4*)&featb[(size_t)(tok8 + 64 * j) * DD + k0_ + k4];    \
    fS = *(const float4*)&selfb[(size_t)tok8 * DD + k0_ + k4];                    \
  } while (0)

  f32x4 accS[4][2] = {};
  LOADA(0);
  for (int kc = 0; kc < 12; ++kc) {
    // convert + stage (RNE for score accuracy)
    #pragma unroll
    for (int j = 0; j < 4; ++j) {
      uint2 p = make_uint2(packrne(fF[j].x, fF[j].y), packrne(fF[j].z, fF[j].w));
      *(uint2*)&sF[tok8 + 64 * j][k4] = p;
    }
    {
      uint2 p = make_uint2(packrne(fS.x, fS.y), packrne(fS.z, fS.w));
      *(uint2*)&sS[tok8][k4] = p;
    }
    __syncthreads();
    if (kc < 11) LOADA(kc + 1);   // T14: in flight during frag-reads + MFMA
    half8 ah[4], bh[2];
    #pragma unroll
    for (int rt = 0; rt < 4; ++rt) ah[rt] = ld_frag8h(&sS[rt * 16 + lam][g * 8]);
    #pragma unroll
    for (int ct = 0; ct < 2; ++ct) bh[ct] = ld_frag8h(&sF[w * 32 + ct * 16 + lam][g * 8]);
    __builtin_amdgcn_s_setprio(1);
    #pragma unroll
    for (int rt = 0; rt < 4; ++rt)
      #pragma unroll
      for (int ct = 0; ct < 2; ++ct)
        accS[rt][ct] = MFMA16(ah[rt], bh[ct], accS[rt][ct], 0, 0, 0);
    __builtin_amdgcn_s_setprio(0);
    __syncthreads();
  }

  // ---------------- Softmax over cols (C layout: col=lane&15, row=g*4+rg) ----------------
  #pragma unroll
  for (int rt = 0; rt < 4; ++rt)
    #pragma unroll
    for (int rg = 0; rg < 4; ++rg) {
      float m = fmaxf(accS[rt][0][rg], accS[rt][1][rg]);
      #pragma unroll
      for (int off = 1; off < 16; off <<= 1) m = fmaxf(m, __shfl_xor(m, off));
      if (lam == 0) sRedM[w][rt * 16 + g * 4 + rg] = m;
    }
  __syncthreads();
  #pragma unroll
  for (int rt = 0; rt < 4; ++rt)
    #pragma unroll
    for (int rg = 0; rg < 4; ++rg) {
      int row = rt * 16 + g * 4 + rg;
      float m = sRedM[0][row];
      #pragma unroll
      for (int ww = 1; ww < 8; ++ww) m = fmaxf(m, sRedM[ww][row]);
      float s = 0.f;
      #pragma unroll
      for (int ct = 0; ct < 2; ++ct) {
        float p = __expf(accS[rt][ct][rg] - m);
        accS[rt][ct][rg] = p;
        s += p;
      }
      #pragma unroll
      for (int off = 1; off < 16; off <<= 1) s += __shfl_xor(s, off);
      if (lam == 0) sRedS[w][row] = s;
    }
  __syncthreads();
  #pragma unroll
  for (int rt = 0; rt < 4; ++rt)
    #pragma unroll
    for (int rg = 0; rg < 4; ++rg) {
      int row = rt * 16 + g * 4 + rg;
      float s = 0.f;
      #pragma unroll
      for (int ww = 0; ww < 8; ++ww) s += sRedS[ww][row];
      float inv = 1.f / s;
      #pragma unroll
      for (int ct = 0; ct < 2; ++ct) {
        int c = w * 32 + ct * 16 + lam;
        _Float16 ph = (_Float16)(accS[rt][ct][rg] * inv);
        sAl[((c >> 3) * QB + row) * 8 + (c & 7)] =
            (short)__builtin_bit_cast(unsigned short, ph);
      }
    }
  __syncthreads();

  // ---------------- PV: O[64][384] = P @ feat, featT staged per 32-token chunk ----------------
  // wave w: d-cols w*48 + dt*16 + lam (dt=0..2)
  float2 L0[6], L1[6];
  #define LOADV(ac_) do {                                                          \
    const int k0_ = (ac_) * 32;                                                    \
    _Pragma("unroll")                                                              \
    for (int i = 0; i < 6; ++i) {                                                  \
      int u = t + i * 512;                                                         \
      int kp = u / 192, d2 = u - kp * 192;                                         \
      const float* fp = &featb[(size_t)(k0_ + kp * 2) * DD + d2 * 2];              \
      L0[i] = *(const float2*)fp;                                                  \
      L1[i] = *(const float2*)(fp + DD);                                           \
    }                                                                              \
  } while (0)

  f32x4 accP[4][3] = {};
  LOADV(0);
  for (int ac = 0; ac < 8; ++ac) {
    #pragma unroll
    for (int i = 0; i < 6; ++i) {       // stage featT[d][tok]: packed token-pairs
      int u = t + i * 512;
      int kp = u / 192, d2 = u - kp * 192;
      int d = d2 * 2;
      *(uint*)&sVt[d][kp * 2]     = packrtz(L0[i].x, L1[i].x);
      *(uint*)&sVt[d + 1][kp * 2] = packrtz(L0[i].y, L1[i].y);
    }
    __syncthreads();
    if (ac < 7) LOADV(ac + 1);          // T14 early-issue
    fragh pf[4];
    half8 vf[3];
    #pragma unroll
    for (int rt = 0; rt < 4; ++rt)
      pf[rt].u = *(const u32x4*)&sAl[((ac * 4 + g) * QB + rt * 16 + lam) * 8];
    #pragma unroll
    for (int dt = 0; dt < 3; ++dt)
      vf[dt] = ld_frag8h(&sVt[w * 48 + dt * 16 + lam][g * 8]);
    __builtin_amdgcn_s_setprio(1);
    #pragma unroll
    for (int rt = 0; rt < 4; ++rt)
      #pragma unroll
      for (int dt = 0; dt < 3; ++dt)
        accP[rt][dt] = MFMA16(pf[rt].h, vf[dt], accP[rt][dt], 0, 0, 0);
    __builtin_amdgcn_s_setprio(0);
    __syncthreads();
  }

  // ---------------- Epilogue: row l2norm over [self|attended], masked pool ----------------
  #pragma unroll
  for (int rt = 0; rt < 4; ++rt)
    #pragma unroll
    for (int rg = 0; rg < 4; ++rg) {
      float s = 0.f;
      #pragma unroll
      for (int dt = 0; dt < 3; ++dt) s += accP[rt][dt][rg] * accP[rt][dt][rg];
      #pragma unroll
      for (int off = 1; off < 16; off <<= 1) s += __shfl_xor(s, off);
      if (lam == 0) sRedM[w][rt * 16 + g * 4 + rg] = s;
    }
  {
    int sr = t >> 3, sc = (t & 7) * 4;
    const float* sp = &selfb[(size_t)sr * DD];
    float ss = 0.f;
    #pragma unroll
    for (int j = 0; j < 12; ++j) {
      float4 v = *(const float4*)&sp[sc + j * 32];
      ss += v.x * v.x + v.y * v.y + v.z * v.z + v.w * v.w;
    }
    ss += __shfl_xor(ss, 1); ss += __shfl_xor(ss, 2); ss += __shfl_xor(ss, 4);
    if ((t & 7) == 0) sSsq[sr] = ss;
  }
  __syncthreads();
  if (t < QB) {
    float tot = sSsq[t];
    #pragma unroll
    for (int ww = 0; ww < 8; ++ww) tot += sRedM[ww][t];
    int mv = msk[(size_t)b * LL + r0 + t];
    sInv[t] = mv ? (1.f / fmaxf(sqrtf(tot), 1e-12f)) : 0.f;
  }
  __syncthreads();
  #pragma unroll
  for (int dt = 0; dt < 3; ++dt) {
    float pa = 0.f;
    #pragma unroll
    for (int rt = 0; rt < 4; ++rt)
      #pragma unroll
      for (int rg = 0; rg < 4; ++rg)
        pa += sInv[rt * 16 + g * 4 + rg] * accP[rt][dt][rg];
    pa += __shfl_xor(pa, 16);
    pa += __shfl_xor(pa, 32);
    if (g == 0) sPool[w * 48 + dt * 16 + lam] = pa;   // unique writer per d
  }
  __syncthreads();
  if (t < DD) {
    float* ac = accum + ((size_t)side * BB + b) * 2 * DD;
    float ps = 0.f;
    const float* sp = selfb + t;
    #pragma unroll 4
    for (int r = 0; r < QB; ++r) ps = fmaf(sInv[r], sp[(size_t)r * DD], ps);
    atomicAdd(&ac[t], ps);
    atomicAdd(&ac[DD + t], sPool[t]);
  }
}

// ---------------- Finalize: divide by mask count, final l2norm ----------------
__global__ __launch_bounds__(256) void finalize_kernel(
    const float* __restrict__ accum, const int* __restrict__ qm,
    const int* __restrict__ am, float* __restrict__ out)
{
  const int b    = blockIdx.x & (BB - 1);
  const int side = blockIdx.x >> 7;
  const int* msk = side ? am : qm;
  const int t = threadIdx.x;
  __shared__ float red[8];

  float c = (float)msk[(size_t)b * LL + t];
  #pragma unroll
  for (int off = 1; off < 64; off <<= 1) c += __shfl_xor(c, off);
  if ((t & 63) == 0) red[t >> 6] = c;
  __syncthreads();
  float cnt = fmaxf(red[0] + red[1] + red[2] + red[3], 1e-9f);

  const float* ac = accum + ((size_t)side * BB + b) * 2 * DD;
  float v[3];
  float ssq = 0.f;
  #pragma unroll
  for (int i = 0; i < 3; ++i) {
    v[i] = ac[t * 3 + i] / cnt;
    ssq += v[i] * v[i];
  }
  #pragma unroll
  for (int off = 1; off < 64; off <<= 1) ssq += __shfl_xor(ssq, off);
  __syncthreads();
  if ((t & 63) == 0) red[t >> 6] = ssq;
  __syncthreads();
  float n = sqrtf(red[0] + red[1] + red[2] + red[3]);
  float inv = 1.f / fmaxf(n, 1e-12f);
  float* ob = out + ((size_t)side * BB + b) * 2 * DD;
  #pragma unroll
  for (int i = 0; i < 3; ++i) ob[t * 3 + i] = v[i] * inv;
}

extern "C" void kernel_launch(void* const* d_in, const int* in_sizes, int n_in,
                              void* d_out, int out_size, void* d_ws, size_t ws_size,
                              hipStream_t stream) {
  const float* qf = (const float*)d_in[0];
  const float* af = (const float*)d_in[1];
  const int*   qm = (const int*)d_in[2];
  const int*   am = (const int*)d_in[3];
  float* out   = (float*)d_out;
  float* accum = (float*)d_ws;   // 2*128*768*4 = 786 KB

  (void)hipMemsetAsync(accum, 0, sizeof(float) * 2 * BB * 2 * DD, stream);
  fused_kernel<<<dim3(1024), 512, 0, stream>>>(qf, af, qm, am, accum);
  finalize_kernel<<<256, 256, 0, stream>>>(accum, qm, am, out);
}